// Round 7
// baseline (4181.385 us; speedup 1.0000x reference)
//
#include <hip/hip_runtime.h>
#include <math.h>

#define BATCH 10
#define HID 128
#define OUT 7
#define MAXLEN 2048
#define NG 512
#define NT 512
#define RINGD 256
#define WSTRIDE 65
#define OFF_STATE ((size_t)BATCH * MAXLEN * OUT)

typedef float float2v __attribute__((ext_vector_type(2)));
typedef float float4v __attribute__((ext_vector_type(4)));

__device__ __forceinline__ float sigm_(float x) { return 1.0f / (1.0f + __expf(-x)); }
__device__ __forceinline__ float tanh_(float x) { return 1.0f - 2.0f / (1.0f + __expf(2.0f * x)); }

__device__ __forceinline__ float2v vlo(float4v v) { return __builtin_shufflevector(v, v, 0, 1); }
__device__ __forceinline__ float2v vhi(float4v v) { return __builtin_shufflevector(v, v, 2, 3); }

// guaranteed packed fp32 FMA (2 MACs/instr)
__device__ __forceinline__ void pk_fma(float2v& acc, float2v w, float2v h) {
    asm("v_pk_fma_f32 %0, %1, %2, %0" : "+v"(acc) : "v"(w), "v"(h));
}

// 3-round butterfly over 8-lane group: xor1, xor2, then row_half_mirror
// (= xor7, valid as xor4 because quads are uniform after rounds 1-2).
__device__ __forceinline__ float grp8_sum(float v) {
    v += __int_as_float(__builtin_amdgcn_update_dpp(0, __float_as_int(v), 0xB1, 0xF, 0xF, true));
    v += __int_as_float(__builtin_amdgcn_update_dpp(0, __float_as_int(v), 0x4E, 0xF, 0xF, true));
    v += __int_as_float(__builtin_amdgcn_update_dpp(0, __float_as_int(v), 0x141, 0xF, 0xF, true));
    return v;
}

__global__
__attribute__((amdgpu_flat_work_group_size(NT, NT), amdgpu_waves_per_eu(2, 2)))
void decoder_rnn_kernel(const float* __restrict__ h0,
                        const float* __restrict__ c0,
                        const float* __restrict__ tonehot,   // (MAXLEN+1, 1, OUT)
                        const void*  __restrict__ tf_raw,    // bool mask, int8 or int32
                        const float* __restrict__ Wih,       // (4H, OUT)
                        const float* __restrict__ Whh,       // (4H, H)
                        const float* __restrict__ bih,
                        const float* __restrict__ bhh,
                        const float* __restrict__ Wout,      // (OUT, H)
                        const float* __restrict__ bout,
                        float* __restrict__ out)
{
    // R23: W_hh K-half [0,64) resident in LDS fp32 (128KB, stride-65 ->
    // conflict-free b128), K-half [64,128) on the R18 remat-from-L2 path.
    // Halves the per-step L1<->L2 weight stream that bounds R18 (2220cyc).
    // Geometry = R18: 8 waves; wave w owns gates [w*64,+64); lane
    // (grp=lane>>3, ksl=lane&7) -> 8 gates x 16 K (4-strided pattern).
    __shared__ __align__(16) float wlds[NG * WSTRIDE];   // 133120 B
    __shared__ float wih_eff[OUT * NG];                  // Wih^T + bias, [x][g]
    __shared__ float ring[RINGD][OUT];                   // RAW logits
    __shared__ __align__(16) float h_lds[HID];
    __shared__ __align__(16) float gates_lds[NG];
    __shared__ unsigned char tgt8[MAXLEN];
    __shared__ unsigned char tf8[MAXLEN];
    __shared__ int tf_byte_mode;

    const int t     = threadIdx.x;
    const int lane  = t & 63;
    const int wv    = t >> 6;         // 0..7
    const int ksl   = lane & 7;       // K sub-slice (4-strided)
    const int grp   = lane >> 3;      // 8-gate group
    const int b     = blockIdx.x;
    const int gbase = wv * 64 + grp * 8;

    // logit weights: waves 0/1, lane-group grp -> logit row grp (zeros grp>=7)
    float4v lw[4];
    #pragma unroll
    for (int c = 0; c < 4; c++) { float4v z = {0.f, 0.f, 0.f, 0.f}; lw[c] = z; }
    if (wv < 2 && grp < OUT) {
        #pragma unroll
        for (int c = 0; c < 4; c++)
            lw[c] = *(const float4v*)&Wout[(size_t)grp * HID + c * 32 + ksl * 4];
    }

    float boutr[OUT];
    #pragma unroll
    for (int j = 0; j < OUT; j++) boutr[j] = bout[j];

    // ---- LDS setup ----
    for (int idx = t; idx < NG * 64; idx += NT) {        // W_hh K<64 -> LDS
        const int g = idx >> 6, k = idx & 63;
        wlds[g * WSTRIDE + k] = Whh[(size_t)g * HID + k];
    }
    for (int idx = t; idx < OUT * NG; idx += NT) {
        int x = idx >> 9, g = idx & (NG - 1);
        wih_eff[idx] = Wih[g * OUT + x] + bih[g] + bhh[g];
    }
    if (t == 0) tf_byte_mode = 0;
    for (int s = t; s < MAXLEN; s += NT) {
        const float* row = tonehot + (size_t)(s + 1) * OUT;
        int idx = 0;
        #pragma unroll
        for (int j = 0; j < OUT; j++) if (row[j] > 0.5f) idx = j;
        tgt8[s] = (unsigned char)idx;
    }
    __syncthreads();
    {   // tf_mask layout detection (int8 bool vs int32) — proven R1-R16
        const unsigned char* tb = (const unsigned char*)tf_raw;
        int mis = 0;
        for (int p = t; p < MAXLEN; p += NT)
            if ((p & 3) && tb[p]) mis = 1;
        if (mis) atomicOr(&tf_byte_mode, 1);
    }
    // ---- state init ----
    float c_reg = 0.f, hv = 0.f;
    if (t < HID) {
        hv    = h0[b * HID + t];
        c_reg = c0[b * HID + t];
        h_lds[t] = hv;
    }
    __syncthreads();
    if (tf_byte_mode) {
        const unsigned char* tb = (const unsigned char*)tf_raw;
        for (int s = t; s < MAXLEN; s += NT) tf8[s] = (tb[s] != 0);
    } else {
        const int* ti = (const int*)tf_raw;
        for (int s = t; s < MAXLEN; s += NT) tf8[s] = (ti[s] != 0);
    }
    __syncthreads();

    float* outlp = out + (size_t)b * MAXLEN * OUT;

    for (int s = 0; s < MAXLEN; s++) {
        // step-control bytes (block-uniform), early
        int tfp = 0, tgp = 0;
        if (s > 0) { tfp = tf8[s - 1]; tgp = tgt8[s - 1]; }

        // tf-step wih prefetch (waves 0/1): xsel known -> hide LDS latency
        float wpre0 = 0.f, wpre1 = 0.f, wpre2 = 0.f, wpre3 = 0.f;
        if (t < HID && tfp) {
            const int xo = tgp * NG;
            wpre0 = wih_eff[xo + t];
            wpre1 = wih_eff[xo + 128 + t];
            wpre2 = wih_eff[xo + 256 + t];
            wpre3 = wih_eff[xo + 384 + t];
        }

        // register-half weight loads (K in [64,128)), issued early so L2
        // latency overlaps the LDS-half FMA block (remat-per-step expected)
        float4v wr[8][2];
        #pragma unroll
        for (int g = 0; g < 8; g++)
            #pragma unroll
            for (int c = 0; c < 2; c++)
                wr[g][c] = *(const float4v*)&Whh[(size_t)(gbase + g) * HID + 64 + c * 32 + ksl * 4];

        // ---- phase 1: matvec. h quads (conflict-free, proven R18) ----
        float4v hc[4];
        #pragma unroll
        for (int c = 0; c < 4; c++)
            hc[c] = *(const float4v*)&h_lds[c * 32 + ksl * 4];

        float2v acc[8];
        #pragma unroll
        for (int g = 0; g < 8; g++) { float2v z = {0.f, 0.f}; acc[g] = z; }
        #pragma unroll
        for (int g = 0; g < 8; g++) {
            const int wb = (gbase + g) * WSTRIDE + ksl * 4;
            const float4v wl0 = *(const float4v*)&wlds[wb];
            const float4v wl1 = *(const float4v*)&wlds[wb + 32];
            pk_fma(acc[g], vlo(wl0), vlo(hc[0]));
            pk_fma(acc[g], vhi(wl0), vhi(hc[0]));
            pk_fma(acc[g], vlo(wl1), vlo(hc[1]));
            pk_fma(acc[g], vhi(wl1), vhi(hc[1]));
            pk_fma(acc[g], vlo(wr[g][0]), vlo(hc[2]));
            pk_fma(acc[g], vhi(wr[g][0]), vhi(hc[2]));
            pk_fma(acc[g], vlo(wr[g][1]), vlo(hc[3]));
            pk_fma(acc[g], vhi(wr[g][1]), vhi(hc[3]));
        }
        float a[8];
        #pragma unroll
        for (int g = 0; g < 8; g++) a[g] = grp8_sum(acc[g][0] + acc[g][1]);

        float al = 0.f;
        if (wv < 2) {
            float2v la = {0.f, 0.f};
            #pragma unroll
            for (int c = 0; c < 4; c++) {
                pk_fma(la, vlo(lw[c]), vlo(hc[c]));
                pk_fma(la, vhi(lw[c]), vhi(hc[c]));
            }
            al = grp8_sum(la[0] + la[1]);    // lane holds raw logit[grp]
        }
        if (ksl == 0) {
            float4v g4a, g4b;
            g4a[0] = a[0]; g4a[1] = a[1]; g4a[2] = a[2]; g4a[3] = a[3];
            g4b[0] = a[4]; g4b[1] = a[5]; g4b[2] = a[6]; g4b[3] = a[7];
            *(float4v*)&gates_lds[gbase]     = g4a;
            *(float4v*)&gates_lds[gbase + 4] = g4b;
        }
        __syncthreads();   // A: gates ready; h_lds reads done

        // ---- phase 2a: pointwise (waves 0,1) ----
        if (t < HID) {
            if (s > 0 && wv == 0 && ksl == 0 && grp < OUT)
                ring[(s - 1) & (RINGD - 1)][grp] = al;   // raw logit
            float w0, w1, w2, w3;
            if (tfp) {
                w0 = wpre0; w1 = wpre1; w2 = wpre2; w3 = wpre3;
            } else {
                int xsel = OUT - 1;
                if (s > 0) {
                    float lg[OUT];
                    #pragma unroll
                    for (int j = 0; j < OUT; j++)
                        lg[j] = __int_as_float(__builtin_amdgcn_readlane(__float_as_int(al), 8 * j)) + boutr[j];
                    float bv = lg[0]; int bi = 0;
                    #pragma unroll
                    for (int j = 1; j < OUT; j++) if (lg[j] > bv) { bv = lg[j]; bi = j; }
                    xsel = bi;
                }
                const int xo = xsel * NG;
                w0 = wih_eff[xo + t];
                w1 = wih_eff[xo + 128 + t];
                w2 = wih_eff[xo + 256 + t];
                w3 = wih_eff[xo + 384 + t];
            }
            const float ri = gates_lds[t]           + w0;
            const float rf = gates_lds[HID + t]     + w1;
            const float rg = gates_lds[2 * HID + t] + w2;
            const float ro = gates_lds[3 * HID + t] + w3;
            const float cn = sigm_(rf) * c_reg + sigm_(ri) * tanh_(rg);
            c_reg = cn;
            hv = sigm_(ro) * tanh_(cn);
            h_lds[t] = hv;
        } else if (t >= 256 && t < 384 && (s & 127) == 1 && s > 128) {
            // ---- phase 2b: deferred log-softmax flush (waves 4-5) ----
            const int step = (s - 129) + (t - 256);      // slot-disjoint from (s-1)
            const int slot = step & (RINGD - 1);
            float v[OUT];
            #pragma unroll
            for (int j = 0; j < OUT; j++) v[j] = ring[slot][j] + boutr[j];
            float mx = v[0];
            #pragma unroll
            for (int j = 1; j < OUT; j++) mx = fmaxf(mx, v[j]);
            float sum = 0.f;
            #pragma unroll
            for (int j = 0; j < OUT; j++) sum += __expf(v[j] - mx);
            const float lse = mx + __logf(sum);
            float* dst = outlp + (size_t)step * OUT;
            #pragma unroll
            for (int j = 0; j < OUT; j++) dst[j] = v[j] - lse;
        }
        __syncthreads();   // C: h(s+1) visible
    }

    // ---- epilogue: raw logits for step 2047 from final h ----
    if (wv < 2) {
        float2v la = {0.f, 0.f};
        #pragma unroll
        for (int c = 0; c < 4; c++) {
            const float4v h4 = *(const float4v*)&h_lds[c * 32 + ksl * 4];
            pk_fma(la, vlo(lw[c]), vlo(h4));
            pk_fma(la, vhi(lw[c]), vhi(h4));
        }
        const float al = grp8_sum(la[0] + la[1]);
        if (wv == 0 && ksl == 0 && grp < OUT)
            ring[(MAXLEN - 1) & (RINGD - 1)][grp] = al;
    }
    __syncthreads();
    if (t < 128) {   // final flush: steps 1920..2047 (regular flush covered <1920)
        const int step = (MAXLEN - 128) + t;
        const int slot = step & (RINGD - 1);
        float v[OUT];
        #pragma unroll
        for (int j = 0; j < OUT; j++) v[j] = ring[slot][j] + boutr[j];
        float mx = v[0];
        #pragma unroll
        for (int j = 1; j < OUT; j++) mx = fmaxf(mx, v[j]);
        float sum = 0.f;
        #pragma unroll
        for (int j = 0; j < OUT; j++) sum += __expf(v[j] - mx);
        const float lse = mx + __logf(sum);
        float* dst = outlp + (size_t)step * OUT;
        #pragma unroll
        for (int j = 0; j < OUT; j++) dst[j] = v[j] - lse;
    }
    if (t < HID) {
        out[OFF_STATE + b * HID + t] = hv;                        // hT
        out[OFF_STATE + BATCH * HID + b * HID + t] = c_reg;       // cT
    }
}

extern "C" void kernel_launch(void* const* d_in, const int* in_sizes, int n_in,
                              void* d_out, int out_size, void* d_ws, size_t ws_size,
                              hipStream_t stream) {
    const float* h0    = (const float*)d_in[0];
    const float* c0    = (const float*)d_in[1];
    const float* toh   = (const float*)d_in[2];
    const void*  tfm   = (const void*) d_in[3];
    const float* Wih   = (const float*)d_in[4];
    const float* Whh   = (const float*)d_in[5];
    const float* bih   = (const float*)d_in[6];
    const float* bhh   = (const float*)d_in[7];
    const float* Wout  = (const float*)d_in[8];
    const float* bout  = (const float*)d_in[9];
    float* out = (float*)d_out;

    decoder_rnn_kernel<<<dim3(BATCH), dim3(NT), 0, stream>>>(
        h0, c0, toh, tfm, Wih, Whh, bih, bhh, Wout, bout, out);
}

// Round 8
// 2512.309 us; speedup vs baseline: 1.6644x; 1.6644x over previous
//
#include <hip/hip_runtime.h>
#include <math.h>

#define BATCH 10
#define HID 128
#define OUT 7
#define MAXLEN 2048
#define NG 512
#define NT 512
#define RINGD 256
#define OFF_STATE ((size_t)BATCH * MAXLEN * OUT)

typedef float float2v __attribute__((ext_vector_type(2)));
typedef float float4v __attribute__((ext_vector_type(4)));

__device__ __forceinline__ float sigm_(float x) { return 1.0f / (1.0f + __expf(-x)); }
__device__ __forceinline__ float tanh_(float x) { return 1.0f - 2.0f / (1.0f + __expf(2.0f * x)); }

__device__ __forceinline__ float2v vlo(float4v v) { return __builtin_shufflevector(v, v, 0, 1); }
__device__ __forceinline__ float2v vhi(float4v v) { return __builtin_shufflevector(v, v, 2, 3); }

// guaranteed packed fp32 FMA (2 MACs/instr)
__device__ __forceinline__ void pk_fma(float2v& acc, float2v w, float2v h) {
    asm("v_pk_fma_f32 %0, %1, %2, %0" : "+v"(acc) : "v"(w), "v"(h));
}

// 3-round butterfly over 8-lane group: xor1, xor2, row_half_mirror (=xor4
// valid because quads are uniform after rounds 1-2).
__device__ __forceinline__ float grp8_sum(float v) {
    v += __int_as_float(__builtin_amdgcn_update_dpp(0, __float_as_int(v), 0xB1, 0xF, 0xF, true));
    v += __int_as_float(__builtin_amdgcn_update_dpp(0, __float_as_int(v), 0x4E, 0xF, 0xF, true));
    v += __int_as_float(__builtin_amdgcn_update_dpp(0, __float_as_int(v), 0x141, 0xF, 0xF, true));
    return v;
}

__global__
__attribute__((amdgpu_flat_work_group_size(NT, NT), amdgpu_waves_per_eu(2, 2)))
void decoder_rnn_kernel(const float* __restrict__ h0,
                        const float* __restrict__ c0,
                        const float* __restrict__ tonehot,   // (MAXLEN+1, 1, OUT)
                        const void*  __restrict__ tf_raw,    // bool mask, int8 or int32
                        const float* __restrict__ Wih,       // (4H, OUT)
                        const float* __restrict__ Whh,       // (4H, H)
                        const float* __restrict__ bih,
                        const float* __restrict__ bhh,
                        const float* __restrict__ Wout,      // (OUT, H)
                        const float* __restrict__ bout,
                        float* __restrict__ out)
{
    // R24: dual-pipe weight sourcing. Per lane (R18 geometry: wave w owns
    // gates [w*64,+64); grp=lane>>3 -> 8 gates, ksl=lane&7 -> 16 K each):
    //  - quads for gates 0-2 + gate3 c<2 (14 quads) come from LDS, stored
    //    PRE-PERMUTED per-lane-contiguous: wlds4[q*512 + t] -> each wave's
    //    ds_read_b128 covers 64 consecutive float4s (conflict-free, m134).
    //  - quads for gate3 c>=2 + gates 4-7 (18 quads) stream from L2 via the
    //    proven remat path (no pins/launder: remat is WANTED here).
    // LDS pipe ~1340cyc and L2 ~1280cyc run in parallel across 8 waves.
    __shared__ __align__(16) float4v wlds4[16 * NT];     // 131072 B, permuted
    __shared__ float wih_eff[OUT * NG];                  // Wih^T + bias, [x][g]
    __shared__ float ring[RINGD][OUT];                   // RAW logits
    __shared__ __align__(16) float h_lds[HID];
    __shared__ __align__(16) float gates_lds[NG];
    __shared__ unsigned char tgt8[MAXLEN];
    __shared__ unsigned char tf8[MAXLEN];
    __shared__ int tf_byte_mode;

    const int t     = threadIdx.x;
    const int lane  = t & 63;
    const int wv    = t >> 6;         // 0..7
    const int ksl   = lane & 7;       // K sub-slice (4-strided)
    const int grp   = lane >> 3;      // 8-gate group
    const int b     = blockIdx.x;
    const int gbase = wv * 64 + grp * 8;

    float boutr[OUT];
    #pragma unroll
    for (int j = 0; j < OUT; j++) boutr[j] = bout[j];

    // ---- LDS setup ----
    // permuted W_hh half: lane's gates 0..3, quads c=0..3 -> wlds4[(g*4+c)*NT + t]
    #pragma unroll
    for (int q = 0; q < 16; q++) {
        const int g = q >> 2, c = q & 3;
        wlds4[q * NT + t] = *(const float4v*)&Whh[(size_t)(gbase + g) * HID + c * 32 + ksl * 4];
    }
    for (int idx = t; idx < OUT * NG; idx += NT) {
        int x = idx >> 9, g = idx & (NG - 1);
        wih_eff[idx] = Wih[g * OUT + x] + bih[g] + bhh[g];
    }
    if (t == 0) tf_byte_mode = 0;
    for (int s = t; s < MAXLEN; s += NT) {
        const float* row = tonehot + (size_t)(s + 1) * OUT;
        int idx = 0;
        #pragma unroll
        for (int j = 0; j < OUT; j++) if (row[j] > 0.5f) idx = j;
        tgt8[s] = (unsigned char)idx;
    }
    __syncthreads();
    {   // tf_mask layout detection (int8 bool vs int32) — proven R1-R16
        const unsigned char* tb = (const unsigned char*)tf_raw;
        int mis = 0;
        for (int p = t; p < MAXLEN; p += NT)
            if ((p & 3) && tb[p]) mis = 1;
        if (mis) atomicOr(&tf_byte_mode, 1);
    }
    // ---- state init ----
    float c_reg = 0.f, hv = 0.f;
    if (t < HID) {
        hv    = h0[b * HID + t];
        c_reg = c0[b * HID + t];
        h_lds[t] = hv;
    }
    __syncthreads();
    if (tf_byte_mode) {
        const unsigned char* tb = (const unsigned char*)tf_raw;
        for (int s = t; s < MAXLEN; s += NT) tf8[s] = (tb[s] != 0);
    } else {
        const int* ti = (const int*)tf_raw;
        for (int s = t; s < MAXLEN; s += NT) tf8[s] = (ti[s] != 0);
    }
    __syncthreads();

    float* outlp = out + (size_t)b * MAXLEN * OUT;

    for (int s = 0; s < MAXLEN; s++) {
        // step-control bytes (block-uniform), early
        int tfp = 0, tgp = 0;
        if (s > 0) { tfp = tf8[s - 1]; tgp = tgt8[s - 1]; }

        // tf-step wih prefetch (waves 0/1): xsel known -> hide LDS latency
        float wpre0 = 0.f, wpre1 = 0.f, wpre2 = 0.f, wpre3 = 0.f;
        if (t < HID && tfp) {
            const int xo = tgp * NG;
            wpre0 = wih_eff[xo + t];
            wpre1 = wih_eff[xo + 128 + t];
            wpre2 = wih_eff[xo + 256 + t];
            wpre3 = wih_eff[xo + 384 + t];
        }

        // ---- stream loads (gate3 c>=2, gates 4-7), issued early ----
        float4v wsA[2];
        #pragma unroll
        for (int c = 0; c < 2; c++)
            wsA[c] = *(const float4v*)&Whh[(size_t)(gbase + 3) * HID + (c + 2) * 32 + ksl * 4];
        float4v wsB[4][4];
        #pragma unroll
        for (int g = 0; g < 4; g++)
            #pragma unroll
            for (int c = 0; c < 4; c++)
                wsB[g][c] = *(const float4v*)&Whh[(size_t)(gbase + 4 + g) * HID + c * 32 + ksl * 4];

        // logit weights (waves 0/1), streamed (remat, tiny)
        float4v lw[4];
        #pragma unroll
        for (int c = 0; c < 4; c++) { float4v z = {0.f, 0.f, 0.f, 0.f}; lw[c] = z; }
        if (wv < 2 && grp < OUT) {
            #pragma unroll
            for (int c = 0; c < 4; c++)
                lw[c] = *(const float4v*)&Wout[(size_t)grp * HID + c * 32 + ksl * 4];
        }

        // ---- h quads (8-way broadcast, conflict-free, proven R18) ----
        float4v hc[4];
        #pragma unroll
        for (int c = 0; c < 4; c++)
            hc[c] = *(const float4v*)&h_lds[c * 32 + ksl * 4];

        // ---- matvec: LDS-fed gates 0-2 + g3-partial, stream rest ----
        float2v acc[8];
        #pragma unroll
        for (int g = 0; g < 8; g++) { float2v z = {0.f, 0.f}; acc[g] = z; }
        #pragma unroll
        for (int g = 0; g < 3; g++)
            #pragma unroll
            for (int c = 0; c < 4; c++) {
                const float4v w = wlds4[(g * 4 + c) * NT + t];
                pk_fma(acc[g], vlo(w), vlo(hc[c]));
                pk_fma(acc[g], vhi(w), vhi(hc[c]));
            }
        {
            const float4v w0 = wlds4[12 * NT + t];
            const float4v w1 = wlds4[13 * NT + t];
            pk_fma(acc[3], vlo(w0), vlo(hc[0]));
            pk_fma(acc[3], vhi(w0), vhi(hc[0]));
            pk_fma(acc[3], vlo(w1), vlo(hc[1]));
            pk_fma(acc[3], vhi(w1), vhi(hc[1]));
            pk_fma(acc[3], vlo(wsA[0]), vlo(hc[2]));
            pk_fma(acc[3], vhi(wsA[0]), vhi(hc[2]));
            pk_fma(acc[3], vlo(wsA[1]), vlo(hc[3]));
            pk_fma(acc[3], vhi(wsA[1]), vhi(hc[3]));
        }
        #pragma unroll
        for (int g = 0; g < 4; g++)
            #pragma unroll
            for (int c = 0; c < 4; c++) {
                pk_fma(acc[4 + g], vlo(wsB[g][c]), vlo(hc[c]));
                pk_fma(acc[4 + g], vhi(wsB[g][c]), vhi(hc[c]));
            }

        float a[8];
        #pragma unroll
        for (int g = 0; g < 8; g++) a[g] = grp8_sum(acc[g][0] + acc[g][1]);

        float al = 0.f;
        if (wv < 2) {
            float2v la = {0.f, 0.f};
            #pragma unroll
            for (int c = 0; c < 4; c++) {
                pk_fma(la, vlo(lw[c]), vlo(hc[c]));
                pk_fma(la, vhi(lw[c]), vhi(hc[c]));
            }
            al = grp8_sum(la[0] + la[1]);    // lane holds raw logit[grp]
        }
        if (ksl == 0) {
            float4v g4a, g4b;
            g4a[0] = a[0]; g4a[1] = a[1]; g4a[2] = a[2]; g4a[3] = a[3];
            g4b[0] = a[4]; g4b[1] = a[5]; g4b[2] = a[6]; g4b[3] = a[7];
            *(float4v*)&gates_lds[gbase]     = g4a;
            *(float4v*)&gates_lds[gbase + 4] = g4b;
        }
        __syncthreads();   // A: gates ready; h_lds reads done

        // ---- phase 2a: pointwise (waves 0,1) ----
        if (t < HID) {
            if (s > 0 && wv == 0 && ksl == 0 && grp < OUT)
                ring[(s - 1) & (RINGD - 1)][grp] = al;   // raw logit
            float w0, w1, w2, w3;
            if (tfp) {
                w0 = wpre0; w1 = wpre1; w2 = wpre2; w3 = wpre3;
            } else {
                int xsel = OUT - 1;
                if (s > 0) {
                    float lg[OUT];
                    #pragma unroll
                    for (int j = 0; j < OUT; j++)
                        lg[j] = __int_as_float(__builtin_amdgcn_readlane(__float_as_int(al), 8 * j)) + boutr[j];
                    float bv = lg[0]; int bi = 0;
                    #pragma unroll
                    for (int j = 1; j < OUT; j++) if (lg[j] > bv) { bv = lg[j]; bi = j; }
                    xsel = bi;
                }
                const int xo = xsel * NG;
                w0 = wih_eff[xo + t];
                w1 = wih_eff[xo + 128 + t];
                w2 = wih_eff[xo + 256 + t];
                w3 = wih_eff[xo + 384 + t];
            }
            const float ri = gates_lds[t]           + w0;
            const float rf = gates_lds[HID + t]     + w1;
            const float rg = gates_lds[2 * HID + t] + w2;
            const float ro = gates_lds[3 * HID + t] + w3;
            const float cn = sigm_(rf) * c_reg + sigm_(ri) * tanh_(rg);
            c_reg = cn;
            hv = sigm_(ro) * tanh_(cn);
            h_lds[t] = hv;
        } else if (t >= 256 && t < 384 && (s & 127) == 1 && s > 128) {
            // ---- phase 2b: deferred log-softmax flush (waves 4-5) ----
            const int step = (s - 129) + (t - 256);      // slot-disjoint from (s-1)
            const int slot = step & (RINGD - 1);
            float v[OUT];
            #pragma unroll
            for (int j = 0; j < OUT; j++) v[j] = ring[slot][j] + boutr[j];
            float mx = v[0];
            #pragma unroll
            for (int j = 1; j < OUT; j++) mx = fmaxf(mx, v[j]);
            float sum = 0.f;
            #pragma unroll
            for (int j = 0; j < OUT; j++) sum += __expf(v[j] - mx);
            const float lse = mx + __logf(sum);
            float* dst = outlp + (size_t)step * OUT;
            #pragma unroll
            for (int j = 0; j < OUT; j++) dst[j] = v[j] - lse;
        }
        __syncthreads();   // C: h(s+1) visible
    }

    // ---- epilogue: raw logits for step 2047 from final h ----
    if (wv < 2) {
        float4v lw[4];
        #pragma unroll
        for (int c = 0; c < 4; c++) { float4v z = {0.f, 0.f, 0.f, 0.f}; lw[c] = z; }
        if (grp < OUT) {
            #pragma unroll
            for (int c = 0; c < 4; c++)
                lw[c] = *(const float4v*)&Wout[(size_t)grp * HID + c * 32 + ksl * 4];
        }
        float2v la = {0.f, 0.f};
        #pragma unroll
        for (int c = 0; c < 4; c++) {
            const float4v h4 = *(const float4v*)&h_lds[c * 32 + ksl * 4];
            pk_fma(la, vlo(lw[c]), vlo(h4));
            pk_fma(la, vhi(lw[c]), vhi(h4));
        }
        const float al = grp8_sum(la[0] + la[1]);
        if (wv == 0 && ksl == 0 && grp < OUT)
            ring[(MAXLEN - 1) & (RINGD - 1)][grp] = al;
    }
    __syncthreads();
    if (t < 128) {   // final flush: steps 1920..2047 (regular flush covered <1920)
        const int step = (MAXLEN - 128) + t;
        const int slot = step & (RINGD - 1);
        float v[OUT];
        #pragma unroll
        for (int j = 0; j < OUT; j++) v[j] = ring[slot][j] + boutr[j];
        float mx = v[0];
        #pragma unroll
        for (int j = 1; j < OUT; j++) mx = fmaxf(mx, v[j]);
        float sum = 0.f;
        #pragma unroll
        for (int j = 0; j < OUT; j++) sum += __expf(v[j] - mx);
        const float lse = mx + __logf(sum);
        float* dst = outlp + (size_t)step * OUT;
        #pragma unroll
        for (int j = 0; j < OUT; j++) dst[j] = v[j] - lse;
    }
    if (t < HID) {
        out[OFF_STATE + b * HID + t] = hv;                        // hT
        out[OFF_STATE + BATCH * HID + b * HID + t] = c_reg;       // cT
    }
}

extern "C" void kernel_launch(void* const* d_in, const int* in_sizes, int n_in,
                              void* d_out, int out_size, void* d_ws, size_t ws_size,
                              hipStream_t stream) {
    const float* h0    = (const float*)d_in[0];
    const float* c0    = (const float*)d_in[1];
    const float* toh   = (const float*)d_in[2];
    const void*  tfm   = (const void*) d_in[3];
    const float* Wih   = (const float*)d_in[4];
    const float* Whh   = (const float*)d_in[5];
    const float* bih   = (const float*)d_in[6];
    const float* bhh   = (const float*)d_in[7];
    const float* Wout  = (const float*)d_in[8];
    const float* bout  = (const float*)d_in[9];
    float* out = (float*)d_out;

    decoder_rnn_kernel<<<dim3(BATCH), dim3(NT), 0, stream>>>(
        h0, c0, toh, tfm, Wih, Whh, bih, bhh, Wout, bout, out);
}